// Round 1
// baseline (206.845 us; speedup 1.0000x reference)
//
#include <hip/hip_runtime.h>
#include <math.h>

#define HOP 256
#define T_START 120
#define NFREQ 19
#define KMIN 13
#define NANGLES 18001

// ---------------------------------------------------------------------------
// K1: one block per DFT coefficient (k,t,c). 64 lanes each sum 8 of the 512
// windowed samples; wave shuffle-reduce; lane 0 writes complex<double> to ws.
// Frame T_START+t starts at sample (T_START-1+t)*HOP (reflect pad is interior
// for these frames). win[n] = sin(pi*n/512) == sqrt(0.5*(1-cos(2pi n/512))).
// ---------------------------------------------------------------------------
__global__ __launch_bounds__(64) void k_dft(const float* __restrict__ x,
                                            double* __restrict__ ws) {
    const int blk  = blockIdx.x;        // blk = k*16 + t*4 + c
    const int k    = blk >> 4;
    const int t    = (blk >> 2) & 3;
    const int c    = blk & 3;
    const int lane = threadIdx.x;
    const int kact = KMIN + k;
    const int base = (T_START - 1 + t) * HOP;

    double xr = 0.0, xi = 0.0;
#pragma unroll
    for (int j = 0; j < 8; ++j) {
        const int n = lane + 64 * j;
        const double v = (double)x[(size_t)(base + n) * 4 + c];
        const double w = sinpi((double)n / 512.0);
        double sp, cp;
        // e^{-2*pi*i*k*n/512}: angle/pi = k*n/256 (exact int division in fp64)
        sincospi((double)(kact * n) / 256.0, &sp, &cp);
        xr += v * w * cp;
        xi -= v * w * sp;
    }
#pragma unroll
    for (int off = 32; off > 0; off >>= 1) {
        xr += __shfl_down(xr, off, 64);
        xi += __shfl_down(xi, off, 64);
    }
    if (lane == 0) {
        ws[2 * blk]     = xr;
        ws[2 * blk + 1] = xi;
    }
}

// ---------------------------------------------------------------------------
// K2: one lane per frequency. Build spt = 0.25 * A A^H (4x4 Hermitian),
// complex Jacobi eigendecomposition (f64, 8 sweeps), noise projector
// P = sum of outer products of 2 smallest eigenvectors, then lag sums:
//   denom(phi) = T0 + 2*Re[Q1 e^{i phi} + Q2 e^{2i phi} + Q3 e^{3i phi}]
// Writes 7 doubles per frequency.
// ---------------------------------------------------------------------------
__global__ __launch_bounds__(64) void k_eig(const double* __restrict__ wsX,
                                            double* __restrict__ tb) {
    const int f = threadIdx.x;
    if (f >= NFREQ) return;

    double Xr[4][4], Xi[4][4];   // [t][c]
#pragma unroll
    for (int t = 0; t < 4; ++t)
#pragma unroll
        for (int c = 0; c < 4; ++c) {
            const int idx = f * 16 + t * 4 + c;
            Xr[t][c] = wsX[2 * idx];
            Xi[t][c] = wsX[2 * idx + 1];
        }

    double Ar[4][4], Ai[4][4], Vr[4][4], Vi[4][4];
#pragma unroll
    for (int a = 0; a < 4; ++a)
#pragma unroll
        for (int d = 0; d < 4; ++d) {
            double ar = 0.0, ai = 0.0;
#pragma unroll
            for (int t = 0; t < 4; ++t) {
                // spt[c][d] = sum_t X[t][c] * conj(X[t][d])
                ar += Xr[t][a] * Xr[t][d] + Xi[t][a] * Xi[t][d];
                ai += Xi[t][a] * Xr[t][d] - Xr[t][a] * Xi[t][d];
            }
            Ar[a][d] = 0.25 * ar;
            Ai[a][d] = 0.25 * ai;
            Vr[a][d] = (a == d) ? 1.0 : 0.0;
            Vi[a][d] = 0.0;
        }

    // Cyclic complex Jacobi. Pivot (p,q): z = A[p][q] = r e^{i alpha};
    // U = [[c, -conj(s)],[s, c]], s = sigma * e^{-i alpha};
    // t = sigma/c is the small root of t^2 - 2*tau*t - 1 = 0,
    // tau = (A_qq - A_pp)/(2r).
    const int PP[6] = {0, 0, 0, 1, 1, 2};
    const int QQ[6] = {1, 2, 3, 2, 3, 3};
    for (int sweep = 0; sweep < 8; ++sweep) {
#pragma unroll
        for (int r6 = 0; r6 < 6; ++r6) {
            const int p = PP[r6], q = QQ[r6];
            const double zr = Ar[p][q], zi = Ai[p][q];
            const double rr = sqrt(zr * zr + zi * zi);
            if (rr < 1e-30) continue;
            const double tau = (Ar[q][q] - Ar[p][p]) / (2.0 * rr);
            const double sq  = sqrt(tau * tau + 1.0);
            const double tt  = (tau >= 0.0) ? (-1.0 / (tau + sq)) : (1.0 / (sq - tau));
            const double cc  = 1.0 / sqrt(1.0 + tt * tt);
            const double sg  = tt * cc;
            const double inv_r = 1.0 / rr;
            const double sr =  sg * zr * inv_r;
            const double si = -sg * zi * inv_r;
            // A <- A * U
#pragma unroll
            for (int kk = 0; kk < 4; ++kk) {
                const double apr = Ar[kk][p], api = Ai[kk][p];
                const double aqr = Ar[kk][q], aqi = Ai[kk][q];
                Ar[kk][p] = cc * apr + sr * aqr - si * aqi;
                Ai[kk][p] = cc * api + sr * aqi + si * aqr;
                Ar[kk][q] = cc * aqr - (sr * apr + si * api);
                Ai[kk][q] = cc * aqi - (sr * api - si * apr);
            }
            // A <- U^H * A
#pragma unroll
            for (int kk = 0; kk < 4; ++kk) {
                const double apr = Ar[p][kk], api = Ai[p][kk];
                const double aqr = Ar[q][kk], aqi = Ai[q][kk];
                Ar[p][kk] = cc * apr + sr * aqr + si * aqi;
                Ai[p][kk] = cc * api + sr * aqi - si * aqr;
                Ar[q][kk] = cc * aqr - (sr * apr - si * api);
                Ai[q][kk] = cc * aqi - (sr * api + si * apr);
            }
            // V <- V * U
#pragma unroll
            for (int kk = 0; kk < 4; ++kk) {
                const double vpr = Vr[kk][p], vpi = Vi[kk][p];
                const double vqr = Vr[kk][q], vqi = Vi[kk][q];
                Vr[kk][p] = cc * vpr + sr * vqr - si * vqi;
                Vi[kk][p] = cc * vpi + sr * vqi + si * vqr;
                Vr[kk][q] = cc * vqr - (sr * vpr + si * vpi);
                Vi[kk][q] = cc * vqi - (sr * vpi - si * vpr);
            }
        }
    }

    // two smallest eigenvalues -> noise subspace (matches eigh ascending [:2])
    double dg[4] = {Ar[0][0], Ar[1][1], Ar[2][2], Ar[3][3]};
    int i0 = 0;
#pragma unroll
    for (int j = 1; j < 4; ++j)
        if (dg[j] < dg[i0]) i0 = j;
    int i1 = (i0 == 0) ? 1 : 0;
#pragma unroll
    for (int j = 0; j < 4; ++j)
        if (j != i0 && dg[j] < dg[i1]) i1 = j;

    double u0r[4], u0i[4], u1r[4], u1i[4];
#pragma unroll
    for (int c = 0; c < 4; ++c) {
        u0r[c] = Vr[c][i0]; u0i[c] = Vi[c][i0];
        u1r[c] = Vr[c][i1]; u1i[c] = Vi[c][i1];
    }

    // P_cd = u0[c]conj(u0[d]) + u1[c]conj(u1[d]); lag sums over c'-c = d
    double T0 = 0.0;
#pragma unroll
    for (int c = 0; c < 4; ++c)
        T0 += u0r[c] * u0r[c] + u0i[c] * u0i[c] + u1r[c] * u1r[c] + u1i[c] * u1i[c];
    double q1r = 0, q1i = 0, q2r = 0, q2i = 0, q3r = 0, q3i = 0;
#pragma unroll
    for (int c = 0; c < 3; ++c) {
        q1r += u0r[c] * u0r[c+1] + u0i[c] * u0i[c+1] + u1r[c] * u1r[c+1] + u1i[c] * u1i[c+1];
        q1i += u0i[c] * u0r[c+1] - u0r[c] * u0i[c+1] + u1i[c] * u1r[c+1] - u1r[c] * u1i[c+1];
    }
#pragma unroll
    for (int c = 0; c < 2; ++c) {
        q2r += u0r[c] * u0r[c+2] + u0i[c] * u0i[c+2] + u1r[c] * u1r[c+2] + u1i[c] * u1i[c+2];
        q2i += u0i[c] * u0r[c+2] - u0r[c] * u0i[c+2] + u1i[c] * u1r[c+2] - u1r[c] * u1i[c+2];
    }
    q3r = u0r[0] * u0r[3] + u0i[0] * u0i[3] + u1r[0] * u1r[3] + u1i[0] * u1i[3];
    q3i = u0i[0] * u0r[3] - u0r[0] * u0i[3] + u1i[0] * u1r[3] - u1r[0] * u1i[3];

    double* o = tb + f * 7;
    o[0] = T0;
    o[1] = q1r; o[2] = q1i;
    o[3] = q2r; o[4] = q2i;
    o[5] = q3r; o[6] = q3i;
}

// ---------------------------------------------------------------------------
// K3: one thread per angle. phi_k = K*sin(theta)*f_k, f_k = 31.25*(13+k).
// cos/sin advanced by fixed rotation over the 19 equally spaced freqs;
// 2phi/3phi via double/triple-angle identities.
// ---------------------------------------------------------------------------
__global__ __launch_bounds__(256) void k_scan(const double* __restrict__ tb_g,
                                              float* __restrict__ out) {
    __shared__ double tb[NFREQ * 7];
    if (threadIdx.x < NFREQ * 7) tb[threadIdx.x] = tb_g[threadIdx.x];
    __syncthreads();
    const int i = blockIdx.x * 256 + threadIdx.x;
    if (i >= NANGLES) return;

    const double deg = -90.0 + 0.01 * (double)i;
    const double sth = sin(deg * (M_PI / 180.0));
    const double KC  = 2.0 * M_PI * 0.1 / 343.0;
    const double a   = KC * sth;

    double c0, s0, cd, sd;
    sincos(a * (31.25 * (double)KMIN), &s0, &c0);  // phi at f = 406.25 Hz
    sincos(a * 31.25, &sd, &cd);                   // step between freq bins

    double sum = 0.0;
#pragma unroll
    for (int k = 0; k < NFREQ; ++k) {
        const double* e = &tb[7 * k];
        const double c2 = c0 * c0 - s0 * s0, s2 = 2.0 * c0 * s0;
        const double c3 = c2 * c0 - s2 * s0, s3 = s2 * c0 + c2 * s0;
        const double den = e[0]
            + 2.0 * (e[1] * c0 - e[2] * s0 + e[3] * c2 - e[4] * s2 + e[5] * c3 - e[6] * s3)
            + 1e-8;
        sum += 1.0 / den;
        const double cn = c0 * cd - s0 * sd;
        s0 = s0 * cd + c0 * sd;
        c0 = cn;
    }
    out[i] = (float)(sum * (1.0 / 19.0));
}

extern "C" void kernel_launch(void* const* d_in, const int* in_sizes, int n_in,
                              void* d_out, int out_size, void* d_ws, size_t ws_size,
                              hipStream_t stream) {
    const float* x = (const float*)d_in[0];
    double* ws = (double*)d_ws;          // [0, 608): X coeffs; [608, 741): table
    float* out = (float*)d_out;

    hipLaunchKernelGGL(k_dft, dim3(NFREQ * 16), dim3(64), 0, stream, x, ws);
    hipLaunchKernelGGL(k_eig, dim3(1), dim3(64), 0, stream, ws, ws + 2 * NFREQ * 16);
    hipLaunchKernelGGL(k_scan, dim3((NANGLES + 255) / 256), dim3(256), 0, stream,
                       ws + 2 * NFREQ * 16, out);
}

// Round 2
// 206.449 us; speedup vs baseline: 1.0019x; 1.0019x over previous
//
#include <hip/hip_runtime.h>
#include <math.h>

#define HOP 256
#define T_START 120
#define NFREQ 19
#define KMIN 13
#define NANGLES 18001

// ---------------------------------------------------------------------------
// K1: one block per (freq k, frame t). 64 lanes; each lane handles 8 samples
// (n = lane + 64j) for ALL 4 mics via one float4 load per sample.
// Trig via recurrence: DFT phase step per j is pi*kact/4 (exact 8-entry
// table), window step is pi/8 (compile-time constants). 2 libm calls/lane.
// win[n] = sin(pi*n/512) == sqrt(0.5*(1-cos(2pi n/512))).
// ---------------------------------------------------------------------------
__constant__ double C8[8] = {1.0, 0.70710678118654752, 0.0, -0.70710678118654752,
                             -1.0, -0.70710678118654752, 0.0, 0.70710678118654752};
__constant__ double S8[8] = {0.0, 0.70710678118654752, 1.0, 0.70710678118654752,
                             0.0, -0.70710678118654752, -1.0, -0.70710678118654752};

__global__ __launch_bounds__(64) void k_dft(const float4* __restrict__ x4,
                                            double* __restrict__ ws) {
    const int blk  = blockIdx.x;        // blk = k*4 + t
    const int k    = blk >> 2;
    const int t    = blk & 3;
    const int lane = threadIdx.x;
    const int kact = KMIN + k;
    const int base = (T_START - 1 + t) * HOP;

    // window: (sw,cw) = sin/cos(pi*lane/512); step pi/8
    const double c8 = 0.98078528040323044913;   // cos(pi/16)? NO -> see below
    // NOTE: step is 64 samples: delta_w = pi*64/512 = pi/8
    const double cw8 = 0.92387953251128675613;  // cos(pi/8)
    const double sw8 = 0.38268343236508977173;  // sin(pi/8)
    (void)c8;
    double sw, cw;
    sincospi((double)lane / 512.0, &sw, &cw);

    // DFT phase: theta_n = pi*kact*n/256; start at n=lane, step pi*kact/4
    double sp, cp;
    sincospi((double)(kact * lane) / 256.0, &sp, &cp);
    const int m = kact & 7;
    const double cd = C8[m], sd = S8[m];

    double xr0 = 0, xi0 = 0, xr1 = 0, xi1 = 0;
    double xr2 = 0, xi2 = 0, xr3 = 0, xi3 = 0;
#pragma unroll
    for (int j = 0; j < 8; ++j) {
        const float4 v = x4[base + lane + 64 * j];
        const double wr = sw * cp;   // w[n]*cos(theta)
        const double wi = sw * sp;   // w[n]*sin(theta)
        xr0 += (double)v.x * wr;  xi0 -= (double)v.x * wi;
        xr1 += (double)v.y * wr;  xi1 -= (double)v.y * wi;
        xr2 += (double)v.z * wr;  xi2 -= (double)v.z * wi;
        xr3 += (double)v.w * wr;  xi3 -= (double)v.w * wi;
        // advance window angle by pi/8
        const double nw = sw * cw8 + cw * sw8;
        cw = cw * cw8 - sw * sw8;
        sw = nw;
        // advance DFT angle by pi*kact/4
        const double np = sp * cd + cp * sd;
        cp = cp * cd - sp * sd;
        sp = np;
    }
#pragma unroll
    for (int off = 32; off > 0; off >>= 1) {
        xr0 += __shfl_down(xr0, off, 64);  xi0 += __shfl_down(xi0, off, 64);
        xr1 += __shfl_down(xr1, off, 64);  xi1 += __shfl_down(xi1, off, 64);
        xr2 += __shfl_down(xr2, off, 64);  xi2 += __shfl_down(xi2, off, 64);
        xr3 += __shfl_down(xr3, off, 64);  xi3 += __shfl_down(xi3, off, 64);
    }
    if (lane == 0) {
        const int idx = k * 16 + t * 4;   // f*16 + t*4 + c
        ws[2 * (idx + 0)] = xr0;  ws[2 * (idx + 0) + 1] = xi0;
        ws[2 * (idx + 1)] = xr1;  ws[2 * (idx + 1) + 1] = xi1;
        ws[2 * (idx + 2)] = xr2;  ws[2 * (idx + 2) + 1] = xi2;
        ws[2 * (idx + 3)] = xr3;  ws[2 * (idx + 3) + 1] = xi3;
    }
}

// ---------------------------------------------------------------------------
// K2: one lane per frequency. spt = 0.25 * A A^H (4x4 Hermitian), complex
// Jacobi (f64, 5 sweeps, pivots grouped in disjoint planes for ILP), noise
// projector P from 2 smallest eigenvectors, then lag sums:
//   denom(phi) = T0 + 2*Re[Q1 e^{i phi} + Q2 e^{2i phi} + Q3 e^{3i phi}]
// ---------------------------------------------------------------------------
__global__ __launch_bounds__(64) void k_eig(const double* __restrict__ wsX,
                                            double* __restrict__ tb) {
    const int f = threadIdx.x;
    if (f >= NFREQ) return;

    double Xr[4][4], Xi[4][4];   // [t][c]
#pragma unroll
    for (int t = 0; t < 4; ++t)
#pragma unroll
        for (int c = 0; c < 4; ++c) {
            const int idx = f * 16 + t * 4 + c;
            Xr[t][c] = wsX[2 * idx];
            Xi[t][c] = wsX[2 * idx + 1];
        }

    double Ar[4][4], Ai[4][4], Vr[4][4], Vi[4][4];
#pragma unroll
    for (int a = 0; a < 4; ++a)
#pragma unroll
        for (int d = 0; d < 4; ++d) {
            double ar = 0.0, ai = 0.0;
#pragma unroll
            for (int t = 0; t < 4; ++t) {
                ar += Xr[t][a] * Xr[t][d] + Xi[t][a] * Xi[t][d];
                ai += Xi[t][a] * Xr[t][d] - Xr[t][a] * Xi[t][d];
            }
            Ar[a][d] = 0.25 * ar;
            Ai[a][d] = 0.25 * ai;
            Vr[a][d] = (a == d) ? 1.0 : 0.0;
            Vi[a][d] = 0.0;
        }

    // Disjoint-plane pairing: (0,1)(2,3) | (0,2)(1,3) | (0,3)(1,2) — adjacent
    // rotations are data-independent, letting sqrt/div latencies overlap.
    const int PP[6] = {0, 2, 0, 1, 0, 1};
    const int QQ[6] = {1, 3, 2, 3, 3, 2};
    for (int sweep = 0; sweep < 5; ++sweep) {
#pragma unroll
        for (int r6 = 0; r6 < 6; ++r6) {
            const int p = PP[r6], q = QQ[r6];
            const double zr = Ar[p][q], zi = Ai[p][q];
            const double rr = sqrt(zr * zr + zi * zi);
            if (rr < 1e-30) continue;
            const double tau = (Ar[q][q] - Ar[p][p]) / (2.0 * rr);
            const double sq  = sqrt(tau * tau + 1.0);
            const double tt  = (tau >= 0.0) ? (-1.0 / (tau + sq)) : (1.0 / (sq - tau));
            const double cc  = 1.0 / sqrt(1.0 + tt * tt);
            const double sg  = tt * cc;
            const double inv_r = 1.0 / rr;
            const double sr =  sg * zr * inv_r;
            const double si = -sg * zi * inv_r;
            // A <- A * U
#pragma unroll
            for (int kk = 0; kk < 4; ++kk) {
                const double apr = Ar[kk][p], api = Ai[kk][p];
                const double aqr = Ar[kk][q], aqi = Ai[kk][q];
                Ar[kk][p] = cc * apr + sr * aqr - si * aqi;
                Ai[kk][p] = cc * api + sr * aqi + si * aqr;
                Ar[kk][q] = cc * aqr - (sr * apr + si * api);
                Ai[kk][q] = cc * aqi - (sr * api - si * apr);
            }
            // A <- U^H * A
#pragma unroll
            for (int kk = 0; kk < 4; ++kk) {
                const double apr = Ar[p][kk], api = Ai[p][kk];
                const double aqr = Ar[q][kk], aqi = Ai[q][kk];
                Ar[p][kk] = cc * apr + sr * aqr + si * aqi;
                Ai[p][kk] = cc * api + sr * aqi - si * aqr;
                Ar[q][kk] = cc * aqr - (sr * apr - si * api);
                Ai[q][kk] = cc * aqi - (sr * api + si * apr);
            }
            // V <- V * U
#pragma unroll
            for (int kk = 0; kk < 4; ++kk) {
                const double vpr = Vr[kk][p], vpi = Vi[kk][p];
                const double vqr = Vr[kk][q], vqi = Vi[kk][q];
                Vr[kk][p] = cc * vpr + sr * vqr - si * vqi;
                Vi[kk][p] = cc * vpi + sr * vqi + si * vqr;
                Vr[kk][q] = cc * vqr - (sr * vpr + si * vpi);
                Vi[kk][q] = cc * vqi - (sr * vpi - si * vpr);
            }
        }
    }

    // two smallest eigenvalues -> noise subspace
    double dg[4] = {Ar[0][0], Ar[1][1], Ar[2][2], Ar[3][3]};
    int i0 = 0;
#pragma unroll
    for (int j = 1; j < 4; ++j)
        if (dg[j] < dg[i0]) i0 = j;
    int i1 = (i0 == 0) ? 1 : 0;
#pragma unroll
    for (int j = 0; j < 4; ++j)
        if (j != i0 && dg[j] < dg[i1]) i1 = j;

    double u0r[4], u0i[4], u1r[4], u1i[4];
#pragma unroll
    for (int c = 0; c < 4; ++c) {
        u0r[c] = Vr[c][i0]; u0i[c] = Vi[c][i0];
        u1r[c] = Vr[c][i1]; u1i[c] = Vi[c][i1];
    }

    double T0 = 0.0;
#pragma unroll
    for (int c = 0; c < 4; ++c)
        T0 += u0r[c] * u0r[c] + u0i[c] * u0i[c] + u1r[c] * u1r[c] + u1i[c] * u1i[c];
    double q1r = 0, q1i = 0, q2r = 0, q2i = 0, q3r = 0, q3i = 0;
#pragma unroll
    for (int c = 0; c < 3; ++c) {
        q1r += u0r[c] * u0r[c+1] + u0i[c] * u0i[c+1] + u1r[c] * u1r[c+1] + u1i[c] * u1i[c+1];
        q1i += u0i[c] * u0r[c+1] - u0r[c] * u0i[c+1] + u1i[c] * u1r[c+1] - u1r[c] * u1i[c+1];
    }
#pragma unroll
    for (int c = 0; c < 2; ++c) {
        q2r += u0r[c] * u0r[c+2] + u0i[c] * u0i[c+2] + u1r[c] * u1r[c+2] + u1i[c] * u1i[c+2];
        q2i += u0i[c] * u0r[c+2] - u0r[c] * u0i[c+2] + u1i[c] * u1r[c+2] - u1r[c] * u1i[c+2];
    }
    q3r = u0r[0] * u0r[3] + u0i[0] * u0i[3] + u1r[0] * u1r[3] + u1i[0] * u1i[3];
    q3i = u0i[0] * u0r[3] - u0r[0] * u0i[3] + u1i[0] * u1r[3] - u1r[0] * u1i[3];

    double* o = tb + f * 7;
    o[0] = T0;
    o[1] = q1r; o[2] = q1i;
    o[3] = q2r; o[4] = q2i;
    o[5] = q3r; o[6] = q3i;
}

// ---------------------------------------------------------------------------
// K3: one thread per angle. phi_k = K*sin(theta)*f_k, f_k = 31.25*(13+k).
// cos/sin advanced by fixed rotation over the 19 equally spaced freqs.
// ---------------------------------------------------------------------------
__global__ __launch_bounds__(256) void k_scan(const double* __restrict__ tb_g,
                                              float* __restrict__ out) {
    __shared__ double tb[NFREQ * 7];
    if (threadIdx.x < NFREQ * 7) tb[threadIdx.x] = tb_g[threadIdx.x];
    __syncthreads();
    const int i = blockIdx.x * 256 + threadIdx.x;
    if (i >= NANGLES) return;

    const double deg = -90.0 + 0.01 * (double)i;
    const double sth = sin(deg * (M_PI / 180.0));
    const double KC  = 2.0 * M_PI * 0.1 / 343.0;
    const double a   = KC * sth;

    double c0, s0, cd, sd;
    sincos(a * (31.25 * (double)KMIN), &s0, &c0);
    sincos(a * 31.25, &sd, &cd);

    double sum = 0.0;
#pragma unroll
    for (int k = 0; k < NFREQ; ++k) {
        const double* e = &tb[7 * k];
        const double c2 = c0 * c0 - s0 * s0, s2 = 2.0 * c0 * s0;
        const double c3 = c2 * c0 - s2 * s0, s3 = s2 * c0 + c2 * s0;
        const double den = e[0]
            + 2.0 * (e[1] * c0 - e[2] * s0 + e[3] * c2 - e[4] * s2 + e[5] * c3 - e[6] * s3)
            + 1e-8;
        sum += 1.0 / den;
        const double cn = c0 * cd - s0 * sd;
        s0 = s0 * cd + c0 * sd;
        c0 = cn;
    }
    out[i] = (float)(sum * (1.0 / 19.0));
}

extern "C" void kernel_launch(void* const* d_in, const int* in_sizes, int n_in,
                              void* d_out, int out_size, void* d_ws, size_t ws_size,
                              hipStream_t stream) {
    const float4* x4 = (const float4*)d_in[0];
    double* ws = (double*)d_ws;          // [0, 608): X coeffs; [608, 741): table
    float* out = (float*)d_out;

    hipLaunchKernelGGL(k_dft, dim3(NFREQ * 4), dim3(64), 0, stream, x4, ws);
    hipLaunchKernelGGL(k_eig, dim3(1), dim3(64), 0, stream, ws, ws + 2 * NFREQ * 16);
    hipLaunchKernelGGL(k_scan, dim3((NANGLES + 255) / 256), dim3(256), 0, stream,
                       ws + 2 * NFREQ * 16, out);
}